// Round 2
// baseline (87.291 us; speedup 1.0000x reference)
//
#include <hip/hip_runtime.h>
#include <math.h>

#define BATCH  64
#define NNODE  1024
#define FDIM   64
#define DEG    8
#define ALPHA  0.2f
#define COPIES 4
#define RPB    (NNODE / COPIES)   // 256 output rows per block

typedef __attribute__((ext_vector_type(8))) short bf16x8;  // 8 bf16 in 4 VGPRs
typedef __attribute__((ext_vector_type(4))) float f32x4;

__device__ __forceinline__ short f2bf(float f) {
    union { float f; unsigned u; } v; v.f = f;
    unsigned r = v.u + 0x7fffu + ((v.u >> 16) & 1u);   // RNE
    return (short)(r >> 16);
}
__device__ __forceinline__ float bflo(unsigned d) {
    union { unsigned u; float f; } v; v.u = d << 16; return v.f;
}
__device__ __forceinline__ float bfhi(unsigned d) {
    union { unsigned u; float f; } v; v.u = d & 0xffff0000u; return v.f;
}

// One block = one (batch, quarter) pair. 1024 threads = 16 waves.
// Phase 1: full-batch h = atoms@W (bf16 MFMA) -> LDS (bf16, XOR-swizzled);
//          s1,s2 derived from the MFMA accumulators (C . a), f32 reduce.
// Phase 2: softmax weights for this quarter's 256 rows -> (addr, weight) LDS.
// Phase 3: half-wave-per-row LDS gather-accumulate, ELU, coalesced store.
// Register budget note: 1024-thread block => hard 128-VGPR cap. Phase-1 live
// state kept to Aw(32) + a-coefs(32) + Bv(8) + C(16) + loads ~= 105 VGPR.
__global__ __launch_bounds__(1024) void gat_fused(
    const float* __restrict__ atoms,   // (B*N, 64) f32
    const int*   __restrict__ edges,   // (B*N, 8) int32
    const float* __restrict__ W,       // (64, 64) f32
    const float* __restrict__ a,       // (128,) f32
    float* __restrict__ out)           // (B*N, 64) f32
{
    __shared__ unsigned long long hsh[NNODE * FDIM / 4];  // 128KB swizzled bf16 h
    __shared__ float  s1l[NNODE];                         // 4KB
    __shared__ float  s2l[NNODE];                         // 4KB
    __shared__ unsigned awl[RPB * DEG * 2];               // 16KB (addr, weight)

    // XCD-bijective mapping: all 4 copies of batch b share bid%8 -> same XCD,
    // so atoms[b] (256KB) is HBM-fetched once and L2-hit by the other 3.
    const int bid = blockIdx.x;
    const int c = (bid >> 3) & 3;                       // copy 0..3
    const int b = (bid & 7) | ((bid >> 5) << 3);        // batch 0..63

    const int tid  = threadIdx.x;
    const int lane = tid & 63;
    const int wv   = tid >> 6;       // wave 0..15
    const int l16  = lane & 15;
    const int qd   = lane >> 4;

    // ---- preload phase-2 edge pair (hides global latency behind phase 1) ----
    const int r2 = tid >> 2;          // block-local row 0..255
    const int j2 = tid & 3;           // edge-pair 0..3
    const int2 ed = *(const int2*)(edges + (size_t)(b * NNODE + c * RPB + r2) * DEG + 2 * j2);

    // ---- W fragments (A operand of transposed MFMA) ----
    // A[m = f = t*16+l16][k = ks*32+qd*8+j] = W[k][f]  => D[f][node] = h^T
    bf16x8 Aw[2][4];
    #pragma unroll
    for (int ks = 0; ks < 2; ++ks)
        #pragma unroll
        for (int t = 0; t < 4; ++t)
            #pragma unroll
            for (int j = 0; j < 8; ++j)
                Aw[ks][t][j] = f2bf(W[(ks * 32 + qd * 8 + j) * FDIM + t * 16 + l16]);

    // ---- per-lane attention coefficients: this lane's f-rows are
    //      f = t*16 + qd*4 + r  (r=0..3, contiguous) ----
    float4 a1c[4], a2c[4];
    #pragma unroll
    for (int t = 0; t < 4; ++t) {
        a1c[t] = *(const float4*)(a + t * 16 + qd * 4);
        a2c[t] = *(const float4*)(a + FDIM + t * 16 + qd * 4);
    }

    // ---- phase 1: GEMM into LDS + scores from accumulators ----
    const float* __restrict__ ab = atoms + (size_t)b * NNODE * FDIM;
    #pragma unroll
    for (int tt = 0; tt < 4; ++tt) {
        const int node = wv * 64 + tt * 16 + l16;
        const float* __restrict__ ar = ab + (size_t)node * FDIM;

        bf16x8 Bv[2];
        #pragma unroll
        for (int ks = 0; ks < 2; ++ks) {
            const float4 p0 = *(const float4*)(ar + ks * 32 + qd * 8);
            const float4 p1 = *(const float4*)(ar + ks * 32 + qd * 8 + 4);
            Bv[ks][0] = f2bf(p0.x); Bv[ks][1] = f2bf(p0.y);
            Bv[ks][2] = f2bf(p0.z); Bv[ks][3] = f2bf(p0.w);
            Bv[ks][4] = f2bf(p1.x); Bv[ks][5] = f2bf(p1.y);
            Bv[ks][6] = f2bf(p1.z); Bv[ks][7] = f2bf(p1.w);
        }

        // Transposed MFMA: D[m=f][n=node]; lane (qd,l16) holds
        // h[node = ..+l16][f = t*16 + qd*4 + r] in C[t][r]
        f32x4 C[4] = {{0,0,0,0},{0,0,0,0},{0,0,0,0},{0,0,0,0}};
        #pragma unroll
        for (int ks = 0; ks < 2; ++ks)
            #pragma unroll
            for (int t = 0; t < 4; ++t)
                C[t] = __builtin_amdgcn_mfma_f32_16x16x32_bf16(Aw[ks][t], Bv[ks], C[t], 0, 0, 0);

        // scores s1/s2 = h . a1 / h . a2 : 16 local f-rows then qd-reduce
        float s1p = 0.f, s2p = 0.f;
        #pragma unroll
        for (int t = 0; t < 4; ++t) {
            s1p = fmaf(C[t][0], a1c[t].x, s1p); s2p = fmaf(C[t][0], a2c[t].x, s2p);
            s1p = fmaf(C[t][1], a1c[t].y, s1p); s2p = fmaf(C[t][1], a2c[t].y, s2p);
            s1p = fmaf(C[t][2], a1c[t].z, s1p); s2p = fmaf(C[t][2], a2c[t].z, s2p);
            s1p = fmaf(C[t][3], a1c[t].w, s1p); s2p = fmaf(C[t][3], a2c[t].w, s2p);
        }
        s1p += __shfl_xor(s1p, 16); s1p += __shfl_xor(s1p, 32);
        s2p += __shfl_xor(s2p, 16); s2p += __shfl_xor(s2p, 32);
        if (qd == 0) { s1l[node] = s1p; s2l[node] = s2p; }

        // packed 8B swizzled h write: f0 = t*16 + qd*4, node col = l16
        #pragma unroll
        for (int t = 0; t < 4; ++t) {
            union { unsigned short s[4]; unsigned long long v; } pk;
            pk.s[0] = (unsigned short)f2bf(C[t][0]);
            pk.s[1] = (unsigned short)f2bf(C[t][1]);
            pk.s[2] = (unsigned short)f2bf(C[t][2]);
            pk.s[3] = (unsigned short)f2bf(C[t][3]);
            const unsigned byte = (unsigned)node * 128u +
                (((unsigned)(t * 32 + qd * 8)) ^ ((unsigned)(node & 15) << 3));
            *(unsigned long long*)((char*)hsh + byte) = pk.v;
        }
    }
    __syncthreads();

    // ---- phase 2: softmax weights, (row, edge-pair)-parallel ----
    {
        // gather all 8 edge ids of the row across the 4-lane group
        const int ax = __shfl_xor(ed.x, 1), ay = __shfl_xor(ed.y, 1);
        const int bx = __shfl_xor(ed.x, 2), by = __shfl_xor(ed.y, 2);
        const int cx = __shfl_xor(ax, 2),   cy = __shfl_xor(ay, 2);

        int e8[8];
        #pragma unroll
        for (int o = 0; o < 4; ++o) {
            const int d = o ^ j2;        // which register holds owner o's pair
            e8[2*o]   = (d == 0) ? ed.x : (d == 1) ? ax : (d == 2) ? bx : cx;
            e8[2*o+1] = (d == 0) ? ed.y : (d == 1) ? ay : (d == 2) ? by : cy;
        }

        const float s1v = s1l[c * RPB + r2];
        float lA = s1v + s2l[ed.x];
        float lB = s1v + s2l[ed.y];
        lA = (lA > 0.f) ? lA : ALPHA * lA;   // LeakyReLU
        lB = (lB > 0.f) ? lB : ALPHA * lB;

        float m = fmaxf(lA, lB);
        m = fmaxf(m, __shfl_xor(m, 1));
        m = fmaxf(m, __shfl_xor(m, 2));

        // dedupe: adjacency is boolean, keep first occurrence only
        bool dupA = false, dupB = false;
        #pragma unroll
        for (int mm = 0; mm < 8; ++mm) {
            dupA = dupA || ((mm < 2 * j2)     && (e8[mm] == ed.x));
            dupB = dupB || ((mm < 2 * j2 + 1) && (e8[mm] == ed.y));
        }

        float wA = dupA ? 0.f : __expf(lA - m);
        float wB = dupB ? 0.f : __expf(lB - m);
        float s = wA + wB;
        s += __shfl_xor(s, 1);
        s += __shfl_xor(s, 2);
        const float inv = 1.f / s;
        wA *= inv; wB *= inv;

        // packed gather base: low 7 bits = swizzle key, disjoint from row base
        union { float f; unsigned u; } fa, fb; fa.f = wA; fb.f = wB;
        uint4 st;
        st.x = (unsigned)(ed.x * 128 + ((ed.x & 15) << 3)); st.y = fa.u;
        st.z = (unsigned)(ed.y * 128 + ((ed.y & 15) << 3)); st.w = fb.u;
        *(uint4*)(awl + (r2 * DEG + 2 * j2) * 2) = st;
    }
    __syncthreads();

    // ---- phase 3: half-wave-per-row gather-accumulate ----
    const int l32 = lane & 31;
    const int h32 = lane >> 5;
    float* __restrict__ ob = out + (size_t)(b * NNODE + c * RPB) * FDIM;
    #pragma unroll 2
    for (int p = 0; p < 8; ++p) {
        const int rowl = wv * 16 + 2 * p + h32;      // half-wave per row
        const uint4* __restrict__ awp = (const uint4*)(awl + rowl * DEG * 2);
        float a0 = 0.f, a1v = 0.f;
        #pragma unroll
        for (int kk = 0; kk < 4; ++kk) {
            const uint4 t = awp[kk];                 // 2 x (packed addr, weight)
            const unsigned d0 = *(const unsigned*)((const char*)hsh +
                                   (t.x ^ (unsigned)(l32 << 2)));
            const unsigned d1 = *(const unsigned*)((const char*)hsh +
                                   (t.z ^ (unsigned)(l32 << 2)));
            union { unsigned u; float f; } w0, w1; w0.u = t.y; w1.u = t.w;
            a0  = fmaf(w0.f, bflo(d0), a0);          // col 2*l32
            a1v = fmaf(w0.f, bfhi(d0), a1v);         // col 2*l32+1
            a0  = fmaf(w1.f, bflo(d1), a0);
            a1v = fmaf(w1.f, bfhi(d1), a1v);
        }
        a0  = (a0  > 0.f) ? a0  : (__expf(a0)  - 1.f);   // ELU
        a1v = (a1v > 0.f) ? a1v : (__expf(a1v) - 1.f);
        *(float2*)(ob + (size_t)rowl * FDIM + 2 * l32) = make_float2(a0, a1v);
    }
}

extern "C" void kernel_launch(void* const* d_in, const int* in_sizes, int n_in,
                              void* d_out, int out_size, void* d_ws, size_t ws_size,
                              hipStream_t stream) {
    const float* atoms = (const float*)d_in[0];   // (64,1024,64) f32
    const int*   edges = (const int*)d_in[1];     // (64,1024,8) int32
    const float* W     = (const float*)d_in[2];   // (64,64) f32
    const float* a     = (const float*)d_in[3];   // (128,1) f32
    float* out = (float*)d_out;                   // (64,1024,64) f32

    gat_fused<<<BATCH * COPIES, 1024, 0, stream>>>(atoms, edges, W, a, out);
}

// Round 4
// 85.312 us; speedup vs baseline: 1.0232x; 1.0232x over previous
//
#include <hip/hip_runtime.h>
#include <hip/hip_bf16.h>
#include <math.h>

#define BATCH  64
#define NNODE  1024
#define FDIM   64
#define DEG    8
#define ALPHA  0.2f
#define COPIES 4
#define RPB    (NNODE / COPIES)   // 256 output rows per block

typedef __attribute__((ext_vector_type(8))) short bf16x8;  // 8 bf16 in 4 VGPRs
typedef __attribute__((ext_vector_type(4))) float f32x4;
typedef __attribute__((ext_vector_type(2))) float f32x2;   // native vec: ok for nontemporal builtin

// Paired f32->bf16 RNE via the HIP intrinsic: compiler pattern-matches this
// into packed conversion (m240: scalar-cast path beats hand-written asm;
// the manual bit-trick RNE was ~4 VALU ops per element and opaque to it).
__device__ __forceinline__ unsigned pkbf(float lo, float hi) {
    union { __hip_bfloat162 h2; unsigned u; } v;
    v.h2 = __float22bfloat162_rn(make_float2(lo, hi));
    return v.u;
}
__device__ __forceinline__ float bflo(unsigned d) {
    union { unsigned u; float f; } v; v.u = d << 16; return v.f;
}
__device__ __forceinline__ float bfhi(unsigned d) {
    union { unsigned u; float f; } v; v.u = d & 0xffff0000u; return v.f;
}

// One block = one (batch, quarter) pair. 1024 threads = 16 waves, 1 block/CU
// (152KB LDS). Phase 1: full-batch h = atoms@W (bf16 MFMA) -> LDS swizzled;
// s1,s2 from the MFMA accumulators (f32). Phase 2: softmax weights ->
// (addr,weight) LDS. Phase 3: half-wave-per-row LDS gather-accumulate.
__global__ __launch_bounds__(1024) void gat_fused(
    const float* __restrict__ atoms,   // (B*N, 64) f32
    const int*   __restrict__ edges,   // (B*N, 8) int32
    const float* __restrict__ W,       // (64, 64) f32
    const float* __restrict__ a,       // (128,) f32
    float* __restrict__ out)           // (B*N, 64) f32
{
    __shared__ unsigned long long hsh[NNODE * FDIM / 4];  // 128KB swizzled bf16 h
    __shared__ float  s1l[NNODE];                         // 4KB
    __shared__ float  s2l[NNODE];                         // 4KB
    __shared__ unsigned awl[RPB * DEG * 2];               // 16KB (addr, weight)

    // XCD-bijective mapping: all 4 copies of batch b share bid&7 -> same XCD,
    // so atoms[b] (256KB) is HBM-fetched once and L2-hit by the other 3.
    const int bid = blockIdx.x;
    const int c = (bid >> 3) & 3;                       // copy 0..3
    const int b = (bid & 7) | ((bid >> 5) << 3);        // batch 0..63

    const int tid  = threadIdx.x;
    const int lane = tid & 63;
    const int wv   = tid >> 6;       // wave 0..15
    const int l16  = lane & 15;
    const int qd   = lane >> 4;

    // ---- preload phase-2 edge pair (hides global latency behind phase 1) ----
    const int r2 = tid >> 2;          // block-local row 0..255
    const int j2 = tid & 3;           // edge-pair 0..3
    const int2 ed = *(const int2*)(edges + (size_t)(b * NNODE + c * RPB + r2) * DEG + 2 * j2);

    // ---- W fragments (A operand of transposed MFMA) ----
    // A[m = f = t*16+l16][k = ks*32+qd*8+j] = W[k][f]  => D[f][node] = h^T
    bf16x8 Aw[2][4];
    #pragma unroll
    for (int ks = 0; ks < 2; ++ks)
        #pragma unroll
        for (int t = 0; t < 4; ++t) {
            const int col = t * 16 + l16;
            const int k0  = ks * 32 + qd * 8;
            union { unsigned u[4]; bf16x8 s; } au;
            #pragma unroll
            for (int jp = 0; jp < 4; ++jp)
                au.u[jp] = pkbf(W[(k0 + 2 * jp) * FDIM + col],
                                W[(k0 + 2 * jp + 1) * FDIM + col]);
            Aw[ks][t] = au.s;
        }

    // ---- per-lane attention coefficients: this lane's f-rows are
    //      f = t*16 + qd*4 + r  (r=0..3, contiguous) ----
    float4 a1c[4], a2c[4];
    #pragma unroll
    for (int t = 0; t < 4; ++t) {
        a1c[t] = *(const float4*)(a + t * 16 + qd * 4);
        a2c[t] = *(const float4*)(a + FDIM + t * 16 + qd * 4);
    }

    // ---- phase 1: GEMM into LDS + scores from accumulators ----
    const float* __restrict__ ab = atoms + (size_t)b * NNODE * FDIM;
    #pragma unroll
    for (int tt = 0; tt < 4; ++tt) {
        const int node = wv * 64 + tt * 16 + l16;
        const float* __restrict__ ar = ab + (size_t)node * FDIM;

        bf16x8 Bv[2];
        #pragma unroll
        for (int ks = 0; ks < 2; ++ks) {
            const float4 p0 = *(const float4*)(ar + ks * 32 + qd * 8);
            const float4 p1 = *(const float4*)(ar + ks * 32 + qd * 8 + 4);
            union { unsigned u[4]; bf16x8 s; } bu;
            bu.u[0] = pkbf(p0.x, p0.y);
            bu.u[1] = pkbf(p0.z, p0.w);
            bu.u[2] = pkbf(p1.x, p1.y);
            bu.u[3] = pkbf(p1.z, p1.w);
            Bv[ks] = bu.s;
        }

        // Transposed MFMA: D[m=f][n=node]; lane (qd,l16) holds
        // h[node = ..+l16][f = t*16 + qd*4 + r] in C[t][r]
        f32x4 C[4] = {{0,0,0,0},{0,0,0,0},{0,0,0,0},{0,0,0,0}};
        #pragma unroll
        for (int ks = 0; ks < 2; ++ks)
            #pragma unroll
            for (int t = 0; t < 4; ++t)
                C[t] = __builtin_amdgcn_mfma_f32_16x16x32_bf16(Aw[ks][t], Bv[ks], C[t], 0, 0, 0);

        // scores s1/s2 = h . a1 / h . a2 : 16 local f-rows then qd-reduce
        float s1p = 0.f, s2p = 0.f;
        #pragma unroll
        for (int t = 0; t < 4; ++t) {
            s1p = fmaf(C[t][0], a1c[t].x, s1p); s2p = fmaf(C[t][0], a2c[t].x, s2p);
            s1p = fmaf(C[t][1], a1c[t].y, s1p); s2p = fmaf(C[t][1], a2c[t].y, s2p);
            s1p = fmaf(C[t][2], a1c[t].z, s1p); s2p = fmaf(C[t][2], a2c[t].z, s2p);
            s1p = fmaf(C[t][3], a1c[t].w, s1p); s2p = fmaf(C[t][3], a2c[t].w, s2p);
        }
        s1p += __shfl_xor(s1p, 16); s1p += __shfl_xor(s1p, 32);
        s2p += __shfl_xor(s2p, 16); s2p += __shfl_xor(s2p, 32);
        if (qd == 0) { s1l[node] = s1p; s2l[node] = s2p; }

        // packed 8B swizzled h write: f0 = t*16 + qd*4, node col = l16
        #pragma unroll
        for (int t = 0; t < 4; ++t) {
            union { unsigned u[2]; unsigned long long v; } pk;
            pk.u[0] = pkbf(C[t][0], C[t][1]);
            pk.u[1] = pkbf(C[t][2], C[t][3]);
            const unsigned byte = (unsigned)node * 128u +
                (((unsigned)(t * 32 + qd * 8)) ^ ((unsigned)(node & 15) << 3));
            *(unsigned long long*)((char*)hsh + byte) = pk.v;
        }
    }
    __syncthreads();

    // ---- phase 2: softmax weights, (row, edge-pair)-parallel ----
    {
        // gather all 8 edge ids of the row across the 4-lane group
        const int ax = __shfl_xor(ed.x, 1), ay = __shfl_xor(ed.y, 1);
        const int bx = __shfl_xor(ed.x, 2), by = __shfl_xor(ed.y, 2);
        const int cx = __shfl_xor(ax, 2),   cy = __shfl_xor(ay, 2);

        int e8[8];
        #pragma unroll
        for (int o = 0; o < 4; ++o) {
            const int d = o ^ j2;        // which register holds owner o's pair
            e8[2*o]   = (d == 0) ? ed.x : (d == 1) ? ax : (d == 2) ? bx : cx;
            e8[2*o+1] = (d == 0) ? ed.y : (d == 1) ? ay : (d == 2) ? by : cy;
        }

        const float s1v = s1l[c * RPB + r2];
        float lA = s1v + s2l[ed.x];
        float lB = s1v + s2l[ed.y];
        lA = (lA > 0.f) ? lA : ALPHA * lA;   // LeakyReLU
        lB = (lB > 0.f) ? lB : ALPHA * lB;

        float m = fmaxf(lA, lB);
        m = fmaxf(m, __shfl_xor(m, 1));
        m = fmaxf(m, __shfl_xor(m, 2));

        // dedupe: adjacency is boolean, keep first occurrence only
        bool dupA = false, dupB = false;
        #pragma unroll
        for (int mm = 0; mm < 8; ++mm) {
            dupA = dupA || ((mm < 2 * j2)     && (e8[mm] == ed.x));
            dupB = dupB || ((mm < 2 * j2 + 1) && (e8[mm] == ed.y));
        }

        float wA = dupA ? 0.f : __expf(lA - m);
        float wB = dupB ? 0.f : __expf(lB - m);
        float s = wA + wB;
        s += __shfl_xor(s, 1);
        s += __shfl_xor(s, 2);
        const float inv = 1.f / s;
        wA *= inv; wB *= inv;

        // packed gather base: low 7 bits = swizzle key, disjoint from row base
        union { float f; unsigned u; } fa, fb; fa.f = wA; fb.f = wB;
        uint4 st;
        st.x = (unsigned)(ed.x * 128 + ((ed.x & 15) << 3)); st.y = fa.u;
        st.z = (unsigned)(ed.y * 128 + ((ed.y & 15) << 3)); st.w = fb.u;
        *(uint4*)(awl + (r2 * DEG + 2 * j2) * 2) = st;
    }
    __syncthreads();

    // ---- phase 3: half-wave-per-row gather-accumulate ----
    const int l32 = lane & 31;
    const int h32 = lane >> 5;
    const unsigned lx = (unsigned)(l32 << 2);
    float* __restrict__ ob = out + (size_t)(b * NNODE + c * RPB) * FDIM;
    #pragma unroll 2
    for (int p = 0; p < 8; ++p) {
        const int rowl = wv * 16 + 2 * p + h32;      // half-wave per row
        const uint4* __restrict__ awp = (const uint4*)(awl + rowl * DEG * 2);
        float a0 = 0.f, a1v = 0.f;
        #pragma unroll
        for (int kk = 0; kk < 4; ++kk) {
            const uint4 t = awp[kk];                 // 2 x (packed addr, weight)
            const unsigned d0 = *(const unsigned*)((const char*)hsh + (t.x ^ lx));
            const unsigned d1 = *(const unsigned*)((const char*)hsh + (t.z ^ lx));
            union { unsigned u; float f; } w0, w1; w0.u = t.y; w1.u = t.w;
            a0  = fmaf(w0.f, bflo(d0), a0);          // col 2*l32
            a1v = fmaf(w0.f, bfhi(d0), a1v);         // col 2*l32+1
            a0  = fmaf(w1.f, bflo(d1), a0);
            a1v = fmaf(w1.f, bfhi(d1), a1v);
        }
        a0  = (a0  > 0.f) ? a0  : (__expf(a0)  - 1.f);   // ELU
        a1v = (a1v > 0.f) ? a1v : (__expf(a1v) - 1.f);
        // streaming store: out is write-once, keep it out of L2
        f32x2 st2; st2.x = a0; st2.y = a1v;
        __builtin_nontemporal_store(st2,
            (f32x2*)(ob + (size_t)rowl * FDIM + 2 * l32));
    }
}

extern "C" void kernel_launch(void* const* d_in, const int* in_sizes, int n_in,
                              void* d_out, int out_size, void* d_ws, size_t ws_size,
                              hipStream_t stream) {
    const float* atoms = (const float*)d_in[0];   // (64,1024,64) f32
    const int*   edges = (const int*)d_in[1];     // (64,1024,8) int32
    const float* W     = (const float*)d_in[2];   // (64,64) f32
    const float* a     = (const float*)d_in[3];   // (128,1) f32
    float* out = (float*)d_out;                   // (64,1024,64) f32

    gat_fused<<<BATCH * COPIES, 1024, 0, stream>>>(atoms, edges, W, a, out);
}